// Round 8
// baseline (219.363 us; speedup 1.0000x reference)
//
#include <hip/hip_runtime.h>
#include <math.h>

#define BATCH 4
#define NQ 2048
#define NKEY 2048
#define DMODEL 512
#define NH 8
#define DHEAD 64
#define BH (BATCH * NH)

typedef __attribute__((ext_vector_type(8))) short short8;
typedef __attribute__((ext_vector_type(4))) float f32x4;

#define MFMA16(a, b, c) __builtin_amdgcn_mfma_f32_16x16x32_bf16((a), (b), (c), 0, 0, 0)

// f32 -> bf16 bits, round-to-nearest-even
static __device__ __forceinline__ unsigned short f2b(float f) {
    union { float f; unsigned u; } v; v.f = f;
    unsigned r = (v.u + 0x7fffu + ((v.u >> 16) & 1u)) >> 16;
    return (unsigned short)r;
}
// bf16 bits -> f32
static __device__ __forceinline__ float b2f(unsigned short u) {
    union { unsigned u; float f; } v; v.u = ((unsigned)u) << 16;
    return v.f;
}
// pack 2 f32 -> 2 bf16 (RNE, identical to f2b) in one instruction
static __device__ __forceinline__ unsigned pkbf(float lo, float hi) {
    unsigned r;
    asm("v_cvt_pk_bf16_f32 %0, %1, %2" : "=v"(r) : "v"(lo), "v"(hi));
    return r;
}
static __device__ __forceinline__ float ex2(float x) {
    return __builtin_amdgcn_exp2f(x);
}

// ---------------------------------------------------------------------------
// Cast both activations f32 -> bf16 (row-major [8192,512])
// ---------------------------------------------------------------------------
__launch_bounds__(256) __global__
void cast_x(const float* __restrict__ a, const float* __restrict__ b,
            unsigned short* __restrict__ da, unsigned short* __restrict__ db) {
    const float* s = blockIdx.y ? b : a;
    unsigned short* d = blockIdx.y ? db : da;
    size_t i = ((size_t)blockIdx.x * 256 + threadIdx.x) * 4;
    float4 v = *(const float4*)(s + i);
    ushort4 o;
    o.x = f2b(v.x); o.y = f2b(v.y); o.z = f2b(v.z); o.w = f2b(v.w);
    *(ushort4*)(d + i) = o;
}

// ---------------------------------------------------------------------------
// Transpose+cast the five 512x512 weights: Wt[n][k] = bf16(W[k][n]).
// Wq (z==0) is pre-scaled by log2(e) so exp(S) = exp2(S').
// ---------------------------------------------------------------------------
__launch_bounds__(256) __global__
void trans_w(const float* __restrict__ w0, const float* __restrict__ w1,
             const float* __restrict__ w2, const float* __restrict__ w3,
             const float* __restrict__ w4, unsigned short* __restrict__ dst) {
    const float* src = (blockIdx.z == 0) ? w0 : (blockIdx.z == 1) ? w1 :
                       (blockIdx.z == 2) ? w2 : (blockIdx.z == 3) ? w3 : w4;
    unsigned short* out = dst + (size_t)blockIdx.z * DMODEL * DMODEL;
    const float sc = (blockIdx.z == 0) ? 1.44269504088896340736f : 1.0f;
    __shared__ float t[32][33];
    const int tx = threadIdx.x & 31, ty = threadIdx.x >> 5;  // 32 x 8
    const int k0 = blockIdx.x * 32, n0 = blockIdx.y * 32;
    #pragma unroll
    for (int j = 0; j < 4; ++j)
        t[ty + j * 8][tx] = src[(size_t)(k0 + ty + j * 8) * DMODEL + n0 + tx];
    __syncthreads();
    #pragma unroll
    for (int j = 0; j < 4; ++j)
        out[(size_t)(n0 + ty + j * 8) * DMODEL + k0 + tx] = f2b(t[tx][ty + j * 8] * sc);
}

// ---------------------------------------------------------------------------
// LDS-staged GEMM core: BM=128, BN=64, BK=64, 256 thr / 4 waves.
// Double-buffered: one barrier per K-tile.  (unchanged this round)
// ---------------------------------------------------------------------------
__device__ __forceinline__
void gemm_core(const unsigned short* __restrict__ A0,   // = A + mTile*K
               const unsigned short* __restrict__ B0,   // = Bt + n0*K
               int K, int tid, unsigned short* Al, unsigned short* Bl,
               f32x4 acc[2][4]) {
    const int w = tid >> 6, lane = tid & 63;
    const int l16 = lane & 15, q4 = lane >> 4;
    const int srow = tid >> 3;           // 0..31
    const int scolb = (tid & 7) * 16;    // byte col 0..112
    const int skoff = (tid & 7) * 8;     // k-element offset

    f32x4 z = {0.f, 0.f, 0.f, 0.f};
    #pragma unroll
    for (int i = 0; i < 2; ++i)
        #pragma unroll
        for (int t = 0; t < 4; ++t) acc[i][t] = z;

    short8 ast[4], bst[2];
    // tile 0 -> regs -> buf0
    #pragma unroll
    for (int c = 0; c < 4; ++c)
        ast[c] = *(const short8*)(A0 + (size_t)(c * 32 + srow) * K + skoff);
    #pragma unroll
    for (int c = 0; c < 2; ++c)
        bst[c] = *(const short8*)(B0 + (size_t)(c * 32 + srow) * K + skoff);
    {
        char* AlB = (char*)Al;
        char* BlB = (char*)Bl;
        #pragma unroll
        for (int c = 0; c < 4; ++c) {
            const int row = c * 32 + srow;
            *(short8*)(AlB + row * 128 + (scolb ^ ((row & 7) << 4))) = ast[c];
        }
        #pragma unroll
        for (int c = 0; c < 2; ++c) {
            const int row = c * 32 + srow;
            *(short8*)(BlB + row * 128 + (scolb ^ ((row & 7) << 4))) = bst[c];
        }
    }
    // prefetch tile 1 into regs
    #pragma unroll
    for (int c = 0; c < 4; ++c)
        ast[c] = *(const short8*)(A0 + (size_t)(c * 32 + srow) * K + 64 + skoff);
    #pragma unroll
    for (int c = 0; c < 2; ++c)
        bst[c] = *(const short8*)(B0 + (size_t)(c * 32 + srow) * K + 64 + skoff);
    __syncthreads();

    const int NT = K >> 6;  // 8
    for (int t = 0; t < NT; ++t) {
        char* AlB = (char*)(Al + (t & 1) * (128 * 64));
        char* BlB = (char*)(Bl + (t & 1) * (64 * 64));
        if (t + 1 < NT) {  // stage tile t+1 into idle buffer; prefetch t+2
            char* AlN = (char*)(Al + ((t + 1) & 1) * (128 * 64));
            char* BlN = (char*)(Bl + ((t + 1) & 1) * (64 * 64));
            #pragma unroll
            for (int c = 0; c < 4; ++c) {
                const int row = c * 32 + srow;
                *(short8*)(AlN + row * 128 + (scolb ^ ((row & 7) << 4))) = ast[c];
            }
            #pragma unroll
            for (int c = 0; c < 2; ++c) {
                const int row = c * 32 + srow;
                *(short8*)(BlN + row * 128 + (scolb ^ ((row & 7) << 4))) = bst[c];
            }
            if (t + 2 < NT) {
                const int kn = (t + 2) * 64;
                #pragma unroll
                for (int c = 0; c < 4; ++c)
                    ast[c] = *(const short8*)(A0 + (size_t)(c * 32 + srow) * K + kn + skoff);
                #pragma unroll
                for (int c = 0; c < 2; ++c)
                    bst[c] = *(const short8*)(B0 + (size_t)(c * 32 + srow) * K + kn + skoff);
            }
        }

        #pragma unroll
        for (int kk = 0; kk < 2; ++kk) {
            const int kb = kk * 64;  // byte base within 128B row
            const int rswA0 = ((w * 32 + l16) & 7) << 4;
            short8 a0 = *(const short8*)(AlB + (w * 32 + l16) * 128 + ((kb + q4 * 16) ^ rswA0));
            short8 a1 = *(const short8*)(AlB + (w * 32 + 16 + l16) * 128 + ((kb + q4 * 16) ^ rswA0));
            short8 bfr[4];
            #pragma unroll
            for (int t2 = 0; t2 < 4; ++t2) {
                const int row = t2 * 16 + l16;
                bfr[t2] = *(const short8*)(BlB + row * 128 + ((kb + q4 * 16) ^ ((row & 7) << 4)));
            }
            #pragma unroll
            for (int t2 = 0; t2 < 4; ++t2) {
                acc[0][t2] = MFMA16(a0, bfr[t2], acc[0][t2]);
                acc[1][t2] = MFMA16(a1, bfr[t2], acc[1][t2]);
            }
        }
        __syncthreads();
    }
}

// ---------------------------------------------------------------------------
// Fused QKV projection: grid.z selects {Q, K, V}.
// ---------------------------------------------------------------------------
__launch_bounds__(256) __global__
void gemm_qkv(const unsigned short* __restrict__ Xq,
              const unsigned short* __restrict__ Xe,
              const unsigned short* __restrict__ Wt,
              unsigned short* __restrict__ Qh,
              unsigned short* __restrict__ Kh,
              unsigned short* __restrict__ Vtb) {
    __shared__ unsigned short Al[2][128 * 64];  // 32KB
    __shared__ unsigned short Bl[2][64 * 64];   // 16KB
    const int tid = threadIdx.x;
    const int zsel = blockIdx.z;
    const int K = DMODEL;
    const unsigned short* A = (zsel == 0) ? Xq : Xe;
    const unsigned short* B0 = Wt + (size_t)zsel * DMODEL * DMODEL + (size_t)(blockIdx.y * 64) * K;
    const unsigned short* A0 = A + (size_t)(blockIdx.x * 128) * K;

    f32x4 acc[2][4];
    gemm_core(A0, B0, K, tid, &Al[0][0], &Bl[0][0], acc);

    const int w = tid >> 6, lane = tid & 63;
    const int l16 = lane & 15, q4 = lane >> 4;
    const int mBase = blockIdx.x * 128 + w * 32;
    const int n0 = blockIdx.y * 64;

    if (zsel < 2) {
        unsigned short* out = (zsel == 0) ? Qh : Kh;
        #pragma unroll
        for (int i = 0; i < 2; ++i)
            #pragma unroll
            for (int t = 0; t < 4; ++t)
                #pragma unroll
                for (int r = 0; r < 4; ++r) {
                    const int m = mBase + i * 16 + q4 * 4 + r;
                    const int n = n0 + t * 16 + l16;
                    out[(((size_t)(m >> 11) * NH + (n >> 6)) * NQ + (m & 2047)) * DHEAD + (n & 63)] = f2b(acc[i][t][r]);
                }
    } else {
        #pragma unroll
        for (int i = 0; i < 2; ++i)
            #pragma unroll
            for (int t = 0; t < 4; ++t) {
                const int m0 = mBase + i * 16 + q4 * 4;  // 4-aligned
                const int n = n0 + t * 16 + l16;
                ushort4 p;
                p.x = f2b(acc[i][t][0]); p.y = f2b(acc[i][t][1]);
                p.z = f2b(acc[i][t][2]); p.w = f2b(acc[i][t][3]);
                *(ushort4*)(Vtb + (((size_t)(m0 >> 11) * NH + (n >> 6)) * DHEAD + (n & 63)) * NKEY + (m0 & 2047)) = p;
            }
    }
}

// ---------------------------------------------------------------------------
// LDS-staged GEMM, modes 2/3.
// ---------------------------------------------------------------------------
template <int MODE>
__launch_bounds__(256) __global__
void gemm_bf16(const unsigned short* __restrict__ A,
               const unsigned short* __restrict__ Bt,
               void* __restrict__ Cout, const float* __restrict__ bias,
               const float* __restrict__ resid, int M, int N, int K) {
    __shared__ unsigned short Al[2][128 * 64];
    __shared__ unsigned short Bl[2][64 * 64];
    const int tid = threadIdx.x;
    const unsigned short* A0 = A + (size_t)(blockIdx.x * 128) * K;
    const unsigned short* B0 = Bt + (size_t)(blockIdx.y * 64) * K;

    f32x4 acc[2][4];
    gemm_core(A0, B0, K, tid, &Al[0][0], &Bl[0][0], acc);

    const int w = tid >> 6, lane = tid & 63;
    const int l16 = lane & 15, q4 = lane >> 4;
    const int mBase = blockIdx.x * 128 + w * 32;
    const int n0 = blockIdx.y * 64;

    #pragma unroll
    for (int i = 0; i < 2; ++i)
        #pragma unroll
        for (int t = 0; t < 4; ++t)
            #pragma unroll
            for (int r = 0; r < 4; ++r) {
                const int m = mBase + i * 16 + q4 * 4 + r;
                const int n = n0 + t * 16 + l16;
                float v = acc[i][t][r];
                if (MODE == 2) {
                    ((unsigned short*)Cout)[(size_t)m * N + n] = f2b(resid[(size_t)m * N + n] - (v + bias[n]));
                } else {
                    ((float*)Cout)[(size_t)m * N + n] = v + bias[n];
                }
            }
}

// ---------------------------------------------------------------------------
// Pass 1: colSrcp[bh][k] = 1 / sum_q exp2(S'[q,k]); cbuf = bf16(colSrcp).
// 512 thr / 8 waves; 128-q dbuf tiles; one barrier/iter.  (unchanged)
// ---------------------------------------------------------------------------
__launch_bounds__(512) __global__
void attn_pass1(const unsigned short* __restrict__ Qh,
                const unsigned short* __restrict__ Kh,
                float* __restrict__ colSrcp,
                unsigned short* __restrict__ cbuf) {
    __shared__ unsigned short Qt[2][128 * 64];  // 2 x 16 KB, swizzled [q][d]
    const int tid = threadIdx.x;
    const int w = tid >> 6, lane = tid & 63;
    const int l16 = lane & 15, q4 = lane >> 4;
    const int bh = blockIdx.y;
    const int kcol0 = blockIdx.x * 128 + w * 16;

    short8 bk0, bk1;
    {
        const unsigned short* Krow = Kh + ((size_t)bh * NKEY + kcol0 + l16) * DHEAD;
        bk0 = *(const short8*)(Krow + q4 * 8);
        bk1 = *(const short8*)(Krow + 32 + q4 * 8);
    }
    const unsigned short* Qb = Qh + (size_t)bh * NQ * DHEAD;
    const int srow = tid >> 3;            // 0..63
    const int skoff = (tid & 7) * 8;
    const int ssw = ((tid & 7) * 16) ^ ((srow & 7) << 4);
    const int rsw = (l16 & 7) << 4;

    f32x4 z = {0.f, 0.f, 0.f, 0.f};
    float csum = 0.f;

    // prologue: tile0 (q 0..127) -> buf0; tile1 into regs
    short8 qa = *(const short8*)(Qb + (size_t)srow * DHEAD + skoff);
    short8 qb = *(const short8*)(Qb + (size_t)(64 + srow) * DHEAD + skoff);
    *(short8*)((char*)Qt[0] + srow * 128 + ssw) = qa;
    *(short8*)((char*)Qt[0] + (64 + srow) * 128 + ssw) = qb;
    qa = *(const short8*)(Qb + (size_t)(128 + srow) * DHEAD + skoff);
    qb = *(const short8*)(Qb + (size_t)(192 + srow) * DHEAD + skoff);
    __syncthreads();

    for (int it = 0; it < 16; ++it) {
        const int q0 = it * 128;
        char* QtB = (char*)Qt[it & 1];
        char* QtN = (char*)Qt[(it & 1) ^ 1];

        if (it < 15) {
            *(short8*)(QtN + srow * 128 + ssw) = qa;
            *(short8*)(QtN + (64 + srow) * 128 + ssw) = qb;
            if (it < 14) {
                qa = *(const short8*)(Qb + (size_t)(q0 + 256 + srow) * DHEAD + skoff);
                qb = *(const short8*)(Qb + (size_t)(q0 + 320 + srow) * DHEAD + skoff);
            }
        }

        #pragma unroll
        for (int qi = 0; qi < 8; ++qi) {
            const int row = qi * 16 + l16;
            short8 a0 = *(const short8*)(QtB + row * 128 + ((q4 * 16) ^ rsw));
            short8 a1 = *(const short8*)(QtB + row * 128 + ((64 + q4 * 16) ^ rsw));
            __builtin_amdgcn_s_setprio(1);
            f32x4 s = MFMA16(a0, bk0, z);
            s = MFMA16(a1, bk1, s);
            __builtin_amdgcn_s_setprio(0);
            csum += ex2(s[0]) + ex2(s[1]) + ex2(s[2]) + ex2(s[3]);
        }
        __syncthreads();
    }
    csum += __shfl_xor(csum, 16, 64);
    csum += __shfl_xor(csum, 32, 64);
    if (q4 == 0) {
        const float c = 1.0f / csum;
        colSrcp[(size_t)bh * NKEY + kcol0 + l16] = c;
        cbuf[(size_t)bh * NKEY + kcol0 + l16] = f2b(c);
    }
}

// ---------------------------------------------------------------------------
// Scale V rows by colSrcp in place: Vtb[bh][d][k] *= colSrcp[bh][k]  (bf16)
// ---------------------------------------------------------------------------
__launch_bounds__(256) __global__
void scale_v(unsigned short* __restrict__ Vtb, const float* __restrict__ colSrcp) {
    const size_t t8 = ((size_t)blockIdx.x * 256 + threadIdx.x) * 8;
    const int k = (int)(t8 & (NKEY - 1));
    const int bh = (int)(t8 >> 17);  // / (DHEAD * NKEY)
    const float* cs = colSrcp + ((size_t)bh << 11) + k;
    short8 v = *(const short8*)(Vtb + t8);
    float4 c0 = *(const float4*)cs;
    float4 c1 = *(const float4*)(cs + 4);
    short8 o;
    o[0] = (short)f2b(b2f((unsigned short)v[0]) * c0.x);
    o[1] = (short)f2b(b2f((unsigned short)v[1]) * c0.y);
    o[2] = (short)f2b(b2f((unsigned short)v[2]) * c0.z);
    o[3] = (short)f2b(b2f((unsigned short)v[3]) * c0.w);
    o[4] = (short)f2b(b2f((unsigned short)v[4]) * c1.x);
    o[5] = (short)f2b(b2f((unsigned short)v[5]) * c1.y);
    o[6] = (short)f2b(b2f((unsigned short)v[6]) * c1.z);
    o[7] = (short)f2b(b2f((unsigned short)v[7]) * c1.w);
    *(short8*)(Vtb + t8) = o;
}

// ---------------------------------------------------------------------------
// Pass 2: F = exp2(S'); O = F @ (cV); rq = F @ c; attnb = bf16(O/(1e-12+rq)).
// Swapped QK + k-slot permutation sigma: thread's own QK outputs ARE its PV
// A-fragment -> E never touches LDS (no write/read/lgkmcnt between MFMAs).
// sigma(q4*8+j) = q4*4+j (j<4) | 16+q4*4+j-4 (j>=4), applied to BOTH the
// E-fragment assembly and the V/c B-fragments (ds_read_b64 pairs), so the
// MFMA k-sum is over the same set -> same result (mod hw dot-tree order).
// K/V tiles [128] dbuf as round 7; one barrier per 128 keys. LDS 64 KB.
// ---------------------------------------------------------------------------
__launch_bounds__(512) __global__
void attn_pass2(const unsigned short* __restrict__ Qh,
                const unsigned short* __restrict__ Kh,
                const unsigned short* __restrict__ Vt,   // pre-scaled by c
                const unsigned short* __restrict__ cb,   // bf16 colSrcp
                unsigned short* __restrict__ attnb) {
    __shared__ unsigned short Kt[2][128 * 64];     // 32 KB
    __shared__ unsigned short Vg[2][2][64 * 64];   // 32 KB (2 k-granules)
    const int tid = threadIdx.x;
    const int w = tid >> 6, lane = tid & 63;
    const int l16 = lane & 15, q4 = lane >> 4;
    const int bh = blockIdx.y;
    const int b = bh >> 3, h = bh & 7;
    const int q0w = blockIdx.x * 128 + w * 16;

    short8 aq0, aq1;
    {
        const unsigned short* Qrow = Qh + ((size_t)bh * NQ + q0w + l16) * DHEAD;
        aq0 = *(const short8*)(Qrow + q4 * 8);
        aq1 = *(const short8*)(Qrow + 32 + q4 * 8);
    }
    const unsigned short* Kb = Kh + (size_t)bh * NKEY * DHEAD;
    const unsigned short* Vb = Vt + (size_t)bh * DHEAD * NKEY;
    const unsigned short* cbb = cb + (size_t)bh * NKEY;

    const int srow = tid >> 3;            // 0..63
    const int skoff = (tid & 7) * 8;
    const int ssw = ((tid & 7) * 16) ^ ((srow & 7) << 4);
    const int rsw = (l16 & 7) << 4;

    f32x4 z = {0.f, 0.f, 0.f, 0.f};
    f32x4 o[4];
    #pragma unroll
    for (int t = 0; t < 4; ++t) o[t] = z;
    f32x4 o5 = z;  // rq accumulator

    // prologue: tile0 (k 0..127) -> buf0; tile1 into regs
    short8 kst[2], vst[2];
    kst[0] = *(const short8*)(Kb + (size_t)srow * DHEAD + skoff);
    kst[1] = *(const short8*)(Kb + (size_t)(64 + srow) * DHEAD + skoff);
    vst[0] = *(const short8*)(Vb + (size_t)srow * NKEY + skoff);
    vst[1] = *(const short8*)(Vb + (size_t)srow * NKEY + 64 + skoff);
    {
        char* K0 = (char*)&Kt[0][0];
        char* V0 = (char*)&Vg[0][0][0];
        *(short8*)(K0 + srow * 128 + ssw) = kst[0];
        *(short8*)(K0 + (64 + srow) * 128 + ssw) = kst[1];
        *(short8*)(V0 + srow * 128 + ssw) = vst[0];
        *(short8*)(V0 + 8192 + srow * 128 + ssw) = vst[1];
    }
    kst[0] = *(const short8*)(Kb + (size_t)(128 + srow) * DHEAD + skoff);
    kst[1] = *(const short8*)(Kb + (size_t)(192 + srow) * DHEAD + skoff);
    vst[0] = *(const short8*)(Vb + (size_t)srow * NKEY + 128 + skoff);
    vst[1] = *(const short8*)(Vb + (size_t)srow * NKEY + 192 + skoff);
    __syncthreads();

    for (int it = 0; it < 16; ++it) {
        const int kb = it * 128;
        char* KtB = (char*)&Kt[it & 1][0];
        char* VgB = (char*)&Vg[it & 1][0][0];

        if (it < 15) {  // stage tile it+1; prefetch tile it+2
            char* KtN = (char*)&Kt[(it & 1) ^ 1][0];
            char* VgN = (char*)&Vg[(it & 1) ^ 1][0][0];
            *(short8*)(KtN + srow * 128 + ssw) = kst[0];
            *(short8*)(KtN + (64 + srow) * 128 + ssw) = kst[1];
            *(short8*)(VgN + srow * 128 + ssw) = vst[0];
            *(short8*)(VgN + 8192 + srow * 128 + ssw) = vst[1];
            if (it < 14) {
                const int kn = kb + 256;
                kst[0] = *(const short8*)(Kb + (size_t)(kn + srow) * DHEAD + skoff);
                kst[1] = *(const short8*)(Kb + (size_t)(kn + 64 + srow) * DHEAD + skoff);
                vst[0] = *(const short8*)(Vb + (size_t)srow * NKEY + kn + skoff);
                vst[1] = *(const short8*)(Vb + (size_t)srow * NKEY + kn + 64 + skoff);
            }
        }

        #pragma unroll
        for (int sub = 0; sub < 4; ++sub) {
            // K fragments (A-operand rows = k)
            short8 bk[2][2];
            #pragma unroll
            for (int jt = 0; jt < 2; ++jt) {
                const int row = sub * 32 + jt * 16 + l16;
                bk[jt][0] = *(const short8*)(KtB + row * 128 + ((q4 * 16) ^ rsw));
                bk[jt][1] = *(const short8*)(KtB + row * 128 + ((64 + q4 * 16) ^ rsw));
            }
            // V fragments under sigma: slot j<4 -> k=q4*4+j, j>=4 -> k=16+q4*4+j-4
            // (two b64 halves per d-block instead of one b128)
            short8 bv[4];
            #pragma unroll
            for (int t = 0; t < 4; ++t) {
                const char* vrow = VgB + (sub >> 1) * 8192 + (t * 16 + l16) * 128;
                const int kbyte = (sub & 1) * 64 + q4 * 8;
                uint2 lo = *(const uint2*)(vrow + (kbyte ^ rsw));
                uint2 hi = *(const uint2*)(vrow + ((kbyte + 32) ^ rsw));
                union { uint4 u; short8 s; } cv;
                cv.u = make_uint4(lo.x, lo.y, hi.x, hi.y);
                bv[t] = cv.s;
            }
            // c fragment under sigma (global, L2-hot; 8B aligned)
            uint2 clo = *(const uint2*)(cbb + kb + sub * 32 + q4 * 4);
            uint2 chi = *(const uint2*)(cbb + kb + sub * 32 + 16 + q4 * 4);
            union { uint4 u; short8 s; } c5;
            c5.u = make_uint4(clo.x, clo.y, chi.x, chi.y);

            // Swapped QK: thread holds S'[q=l16][k = kb+sub*32+jt*16+q4*4+r]
            unsigned ew[4];
            #pragma unroll
            for (int jt = 0; jt < 2; ++jt) {
                __builtin_amdgcn_s_setprio(1);
                f32x4 st = MFMA16(bk[jt][0], aq0, z);
                st = MFMA16(bk[jt][1], aq1, st);
                __builtin_amdgcn_s_setprio(0);
                ew[jt * 2]     = pkbf(ex2(st[0]), ex2(st[1]));
                ew[jt * 2 + 1] = pkbf(ex2(st[2]), ex2(st[3]));
            }
            union { uint4 u; short8 s; } ea;
            ea.u = make_uint4(ew[0], ew[1], ew[2], ew[3]);

            __builtin_amdgcn_s_setprio(1);
            #pragma unroll
            for (int t = 0; t < 4; ++t)
                o[t] = MFMA16(ea.s, bv[t], o[t]);
            o5 = MFMA16(ea.s, c5.s, o5);
            __builtin_amdgcn_s_setprio(0);
        }
        __syncthreads();
    }

    float rr[4];
    #pragma unroll
    for (int r = 0; r < 4; ++r) rr[r] = 1.0f / (1e-12f + o5[r]);
    #pragma unroll
    for (int t = 0; t < 4; ++t)
        #pragma unroll
        for (int r = 0; r < 4; ++r) {
            const int q = q0w + q4 * 4 + r;
            attnb[((size_t)b * NQ + q) * DMODEL + h * DHEAD + t * 16 + l16] =
                f2b(o[t][r] * rr[r]);
        }
}

// ---------------------------------------------------------------------------
extern "C" void kernel_launch(void* const* d_in, const int* in_sizes, int n_in,
                              void* d_out, int out_size, void* d_ws, size_t ws_size,
                              hipStream_t stream) {
    const float* init_query = (const float*)d_in[0];
    const float* embedding  = (const float*)d_in[1];
    const float* Wq = (const float*)d_in[2];
    const float* Wk = (const float*)d_in[3];
    const float* Wv = (const float*)d_in[4];
    const float* W0 = (const float*)d_in[5];
    const float* b0 = (const float*)d_in[6];
    const float* W1 = (const float*)d_in[7];
    const float* b1 = (const float*)d_in[8];
    float* out = (float*)d_out;

    const size_t ACT = (size_t)BATCH * NQ * DMODEL;   // 4M elements
    const size_t WEL = (size_t)DMODEL * DMODEL;       // 256K elements

    unsigned short* Xq   = (unsigned short*)d_ws;          // bf16 init_query
    unsigned short* Xe   = Xq + ACT;                       // bf16 embedding
    unsigned short* Wt   = Xe + ACT;                       // 5 transposed weights
    unsigned short* Qh   = Wt + 5 * WEL;                   // [bh][q][d]
    unsigned short* Kh   = Qh + ACT;                       // [bh][k][d]
    unsigned short* Vtb  = Kh + ACT;                       // [bh][d][k]
    unsigned short* attnb= Vtb + ACT;                      // [8192][512]
    unsigned short* ybuf = attnb + ACT;                    // [8192][512]
    float* colSrcp = (float*)(ybuf + ACT);                 // [bh][k] f32

    // cbuf (bf16 colSrcp) aliases ybuf (dead until the W0-GEMM).
    unsigned short* cbuf = ybuf;

    unsigned short* W0t = Wt + 3 * WEL;
    unsigned short* W1t = Wt + 4 * WEL;

    const int M = BATCH * NQ;  // 8192
    dim3 blk(256);
    dim3 blk512(512);
    dim3 gGemm(M / 128, DMODEL / 64);  // 64 x 8

    cast_x<<<dim3(ACT / 1024, 2), blk, 0, stream>>>(init_query, embedding, Xq, Xe);
    trans_w<<<dim3(16, 16, 5), blk, 0, stream>>>(Wq, Wk, Wv, W0, W1, Wt);

    gemm_qkv<<<dim3(M / 128, DMODEL / 64, 3), blk, 0, stream>>>(Xq, Xe, Wt, Qh, Kh, Vtb);

    attn_pass1<<<dim3(NKEY / 128, BH), blk512, 0, stream>>>(Qh, Kh, colSrcp, cbuf);
    scale_v<<<dim3(ACT / 2048), blk, 0, stream>>>(Vtb, colSrcp);
    attn_pass2<<<dim3(NQ / 128, BH), blk512, 0, stream>>>(Qh, Kh, Vtb, cbuf, attnb);

    gemm_bf16<2><<<gGemm, blk, 0, stream>>>(attnb, W0t, ybuf, b0, init_query, M, DMODEL, DMODEL);
    gemm_bf16<3><<<gGemm, blk, 0, stream>>>(ybuf, W1t, out, b1, nullptr, M, DMODEL, DMODEL);
}

// Round 10
// 213.504 us; speedup vs baseline: 1.0274x; 1.0274x over previous
//
#include <hip/hip_runtime.h>
#include <math.h>

#define BATCH 4
#define NQ 2048
#define NKEY 2048
#define DMODEL 512
#define NH 8
#define DHEAD 64
#define BH (BATCH * NH)

typedef __attribute__((ext_vector_type(8))) short short8;
typedef __attribute__((ext_vector_type(4))) float f32x4;

#define MFMA16(a, b, c) __builtin_amdgcn_mfma_f32_16x16x32_bf16((a), (b), (c), 0, 0, 0)

// f32 -> bf16 bits, round-to-nearest-even
static __device__ __forceinline__ unsigned short f2b(float f) {
    union { float f; unsigned u; } v; v.f = f;
    unsigned r = (v.u + 0x7fffu + ((v.u >> 16) & 1u)) >> 16;
    return (unsigned short)r;
}
// bf16 bits -> f32
static __device__ __forceinline__ float b2f(unsigned short u) {
    union { unsigned u; float f; } v; v.u = ((unsigned)u) << 16;
    return v.f;
}
// pack 2 f32 -> 2 bf16 (RNE, identical to f2b) in one instruction
static __device__ __forceinline__ unsigned pkbf(float lo, float hi) {
    unsigned r;
    asm("v_cvt_pk_bf16_f32 %0, %1, %2" : "=v"(r) : "v"(lo), "v"(hi));
    return r;
}
static __device__ __forceinline__ float ex2(float x) {
    return __builtin_amdgcn_exp2f(x);
}

// ---------------------------------------------------------------------------
// Cast both activations f32 -> bf16 (row-major [8192,512])
// ---------------------------------------------------------------------------
__launch_bounds__(256) __global__
void cast_x(const float* __restrict__ a, const float* __restrict__ b,
            unsigned short* __restrict__ da, unsigned short* __restrict__ db) {
    const float* s = blockIdx.y ? b : a;
    unsigned short* d = blockIdx.y ? db : da;
    size_t i = ((size_t)blockIdx.x * 256 + threadIdx.x) * 4;
    float4 v = *(const float4*)(s + i);
    ushort4 o;
    o.x = f2b(v.x); o.y = f2b(v.y); o.z = f2b(v.z); o.w = f2b(v.w);
    *(ushort4*)(d + i) = o;
}

// ---------------------------------------------------------------------------
// Transpose+cast the five 512x512 weights: Wt[n][k] = bf16(W[k][n]).
// Wq (z==0) is pre-scaled by log2(e) so exp(S) = exp2(S').
// ---------------------------------------------------------------------------
__launch_bounds__(256) __global__
void trans_w(const float* __restrict__ w0, const float* __restrict__ w1,
             const float* __restrict__ w2, const float* __restrict__ w3,
             const float* __restrict__ w4, unsigned short* __restrict__ dst) {
    const float* src = (blockIdx.z == 0) ? w0 : (blockIdx.z == 1) ? w1 :
                       (blockIdx.z == 2) ? w2 : (blockIdx.z == 3) ? w3 : w4;
    unsigned short* out = dst + (size_t)blockIdx.z * DMODEL * DMODEL;
    const float sc = (blockIdx.z == 0) ? 1.44269504088896340736f : 1.0f;
    __shared__ float t[32][33];
    const int tx = threadIdx.x & 31, ty = threadIdx.x >> 5;  // 32 x 8
    const int k0 = blockIdx.x * 32, n0 = blockIdx.y * 32;
    #pragma unroll
    for (int j = 0; j < 4; ++j)
        t[ty + j * 8][tx] = src[(size_t)(k0 + ty + j * 8) * DMODEL + n0 + tx];
    __syncthreads();
    #pragma unroll
    for (int j = 0; j < 4; ++j)
        out[(size_t)(n0 + ty + j * 8) * DMODEL + k0 + tx] = f2b(t[tx][ty + j * 8] * sc);
}

// ---------------------------------------------------------------------------
// LDS-staged GEMM core: BM=128, BN=64, BK=64, 256 thr / 4 waves.
// Double-buffered: one barrier per K-tile.  (unchanged)
// ---------------------------------------------------------------------------
__device__ __forceinline__
void gemm_core(const unsigned short* __restrict__ A0,   // = A + mTile*K
               const unsigned short* __restrict__ B0,   // = Bt + n0*K
               int K, int tid, unsigned short* Al, unsigned short* Bl,
               f32x4 acc[2][4]) {
    const int w = tid >> 6, lane = tid & 63;
    const int l16 = lane & 15, q4 = lane >> 4;
    const int srow = tid >> 3;           // 0..31
    const int scolb = (tid & 7) * 16;    // byte col 0..112
    const int skoff = (tid & 7) * 8;     // k-element offset

    f32x4 z = {0.f, 0.f, 0.f, 0.f};
    #pragma unroll
    for (int i = 0; i < 2; ++i)
        #pragma unroll
        for (int t = 0; t < 4; ++t) acc[i][t] = z;

    short8 ast[4], bst[2];
    // tile 0 -> regs -> buf0
    #pragma unroll
    for (int c = 0; c < 4; ++c)
        ast[c] = *(const short8*)(A0 + (size_t)(c * 32 + srow) * K + skoff);
    #pragma unroll
    for (int c = 0; c < 2; ++c)
        bst[c] = *(const short8*)(B0 + (size_t)(c * 32 + srow) * K + skoff);
    {
        char* AlB = (char*)Al;
        char* BlB = (char*)Bl;
        #pragma unroll
        for (int c = 0; c < 4; ++c) {
            const int row = c * 32 + srow;
            *(short8*)(AlB + row * 128 + (scolb ^ ((row & 7) << 4))) = ast[c];
        }
        #pragma unroll
        for (int c = 0; c < 2; ++c) {
            const int row = c * 32 + srow;
            *(short8*)(BlB + row * 128 + (scolb ^ ((row & 7) << 4))) = bst[c];
        }
    }
    // prefetch tile 1 into regs
    #pragma unroll
    for (int c = 0; c < 4; ++c)
        ast[c] = *(const short8*)(A0 + (size_t)(c * 32 + srow) * K + 64 + skoff);
    #pragma unroll
    for (int c = 0; c < 2; ++c)
        bst[c] = *(const short8*)(B0 + (size_t)(c * 32 + srow) * K + 64 + skoff);
    __syncthreads();

    const int NT = K >> 6;  // 8
    for (int t = 0; t < NT; ++t) {
        char* AlB = (char*)(Al + (t & 1) * (128 * 64));
        char* BlB = (char*)(Bl + (t & 1) * (64 * 64));
        if (t + 1 < NT) {  // stage tile t+1 into idle buffer; prefetch t+2
            char* AlN = (char*)(Al + ((t + 1) & 1) * (128 * 64));
            char* BlN = (char*)(Bl + ((t + 1) & 1) * (64 * 64));
            #pragma unroll
            for (int c = 0; c < 4; ++c) {
                const int row = c * 32 + srow;
                *(short8*)(AlN + row * 128 + (scolb ^ ((row & 7) << 4))) = ast[c];
            }
            #pragma unroll
            for (int c = 0; c < 2; ++c) {
                const int row = c * 32 + srow;
                *(short8*)(BlN + row * 128 + (scolb ^ ((row & 7) << 4))) = bst[c];
            }
            if (t + 2 < NT) {
                const int kn = (t + 2) * 64;
                #pragma unroll
                for (int c = 0; c < 4; ++c)
                    ast[c] = *(const short8*)(A0 + (size_t)(c * 32 + srow) * K + kn + skoff);
                #pragma unroll
                for (int c = 0; c < 2; ++c)
                    bst[c] = *(const short8*)(B0 + (size_t)(c * 32 + srow) * K + kn + skoff);
            }
        }

        #pragma unroll
        for (int kk = 0; kk < 2; ++kk) {
            const int kb = kk * 64;  // byte base within 128B row
            const int rswA0 = ((w * 32 + l16) & 7) << 4;
            short8 a0 = *(const short8*)(AlB + (w * 32 + l16) * 128 + ((kb + q4 * 16) ^ rswA0));
            short8 a1 = *(const short8*)(AlB + (w * 32 + 16 + l16) * 128 + ((kb + q4 * 16) ^ rswA0));
            short8 bfr[4];
            #pragma unroll
            for (int t2 = 0; t2 < 4; ++t2) {
                const int row = t2 * 16 + l16;
                bfr[t2] = *(const short8*)(BlB + row * 128 + ((kb + q4 * 16) ^ ((row & 7) << 4)));
            }
            #pragma unroll
            for (int t2 = 0; t2 < 4; ++t2) {
                acc[0][t2] = MFMA16(a0, bfr[t2], acc[0][t2]);
                acc[1][t2] = MFMA16(a1, bfr[t2], acc[1][t2]);
            }
        }
        __syncthreads();
    }
}

// ---------------------------------------------------------------------------
// Fused QKV projection: grid.z selects {Q, K, V}.
// ---------------------------------------------------------------------------
__launch_bounds__(256) __global__
void gemm_qkv(const unsigned short* __restrict__ Xq,
              const unsigned short* __restrict__ Xe,
              const unsigned short* __restrict__ Wt,
              unsigned short* __restrict__ Qh,
              unsigned short* __restrict__ Kh,
              unsigned short* __restrict__ Vtb) {
    __shared__ unsigned short Al[2][128 * 64];  // 32KB
    __shared__ unsigned short Bl[2][64 * 64];   // 16KB
    const int tid = threadIdx.x;
    const int zsel = blockIdx.z;
    const int K = DMODEL;
    const unsigned short* A = (zsel == 0) ? Xq : Xe;
    const unsigned short* B0 = Wt + (size_t)zsel * DMODEL * DMODEL + (size_t)(blockIdx.y * 64) * K;
    const unsigned short* A0 = A + (size_t)(blockIdx.x * 128) * K;

    f32x4 acc[2][4];
    gemm_core(A0, B0, K, tid, &Al[0][0], &Bl[0][0], acc);

    const int w = tid >> 6, lane = tid & 63;
    const int l16 = lane & 15, q4 = lane >> 4;
    const int mBase = blockIdx.x * 128 + w * 32;
    const int n0 = blockIdx.y * 64;

    if (zsel < 2) {
        unsigned short* out = (zsel == 0) ? Qh : Kh;
        #pragma unroll
        for (int i = 0; i < 2; ++i)
            #pragma unroll
            for (int t = 0; t < 4; ++t)
                #pragma unroll
                for (int r = 0; r < 4; ++r) {
                    const int m = mBase + i * 16 + q4 * 4 + r;
                    const int n = n0 + t * 16 + l16;
                    out[(((size_t)(m >> 11) * NH + (n >> 6)) * NQ + (m & 2047)) * DHEAD + (n & 63)] = f2b(acc[i][t][r]);
                }
    } else {
        #pragma unroll
        for (int i = 0; i < 2; ++i)
            #pragma unroll
            for (int t = 0; t < 4; ++t) {
                const int m0 = mBase + i * 16 + q4 * 4;  // 4-aligned
                const int n = n0 + t * 16 + l16;
                ushort4 p;
                p.x = f2b(acc[i][t][0]); p.y = f2b(acc[i][t][1]);
                p.z = f2b(acc[i][t][2]); p.w = f2b(acc[i][t][3]);
                *(ushort4*)(Vtb + (((size_t)(m0 >> 11) * NH + (n >> 6)) * DHEAD + (n & 63)) * NKEY + (m0 & 2047)) = p;
            }
    }
}

// ---------------------------------------------------------------------------
// LDS-staged GEMM, modes 2/3.
// ---------------------------------------------------------------------------
template <int MODE>
__launch_bounds__(256) __global__
void gemm_bf16(const unsigned short* __restrict__ A,
               const unsigned short* __restrict__ Bt,
               void* __restrict__ Cout, const float* __restrict__ bias,
               const float* __restrict__ resid, int M, int N, int K) {
    __shared__ unsigned short Al[2][128 * 64];
    __shared__ unsigned short Bl[2][64 * 64];
    const int tid = threadIdx.x;
    const unsigned short* A0 = A + (size_t)(blockIdx.x * 128) * K;
    const unsigned short* B0 = Bt + (size_t)(blockIdx.y * 64) * K;

    f32x4 acc[2][4];
    gemm_core(A0, B0, K, tid, &Al[0][0], &Bl[0][0], acc);

    const int w = tid >> 6, lane = tid & 63;
    const int l16 = lane & 15, q4 = lane >> 4;
    const int mBase = blockIdx.x * 128 + w * 32;
    const int n0 = blockIdx.y * 64;

    #pragma unroll
    for (int i = 0; i < 2; ++i)
        #pragma unroll
        for (int t = 0; t < 4; ++t)
            #pragma unroll
            for (int r = 0; r < 4; ++r) {
                const int m = mBase + i * 16 + q4 * 4 + r;
                const int n = n0 + t * 16 + l16;
                float v = acc[i][t][r];
                if (MODE == 2) {
                    ((unsigned short*)Cout)[(size_t)m * N + n] = f2b(resid[(size_t)m * N + n] - (v + bias[n]));
                } else {
                    ((float*)Cout)[(size_t)m * N + n] = v + bias[n];
                }
            }
}

// ---------------------------------------------------------------------------
// Pass 1: colSrcp[bh][k] = 1 / sum_q exp2(S'[q,k]); cbuf = bf16(colSrcp) in
// SIGMA-PERMUTED order (within each 32-k granule: group g holds k in
// {4g..4g+3, 16+4g..16+4g+3}) so pass2 reads its c-fragment as one 16B load.
// ---------------------------------------------------------------------------
__launch_bounds__(512) __global__
void attn_pass1(const unsigned short* __restrict__ Qh,
                const unsigned short* __restrict__ Kh,
                float* __restrict__ colSrcp,
                unsigned short* __restrict__ cbuf) {
    __shared__ unsigned short Qt[2][128 * 64];  // 2 x 16 KB, swizzled [q][d]
    const int tid = threadIdx.x;
    const int w = tid >> 6, lane = tid & 63;
    const int l16 = lane & 15, q4 = lane >> 4;
    const int bh = blockIdx.y;
    const int kcol0 = blockIdx.x * 128 + w * 16;

    short8 bk0, bk1;
    {
        const unsigned short* Krow = Kh + ((size_t)bh * NKEY + kcol0 + l16) * DHEAD;
        bk0 = *(const short8*)(Krow + q4 * 8);
        bk1 = *(const short8*)(Krow + 32 + q4 * 8);
    }
    const unsigned short* Qb = Qh + (size_t)bh * NQ * DHEAD;
    const int srow = tid >> 3;            // 0..63
    const int skoff = (tid & 7) * 8;
    const int ssw = ((tid & 7) * 16) ^ ((srow & 7) << 4);
    const int rsw = (l16 & 7) << 4;

    f32x4 z = {0.f, 0.f, 0.f, 0.f};
    float csum = 0.f;

    // prologue: tile0 (q 0..127) -> buf0; tile1 into regs
    short8 qa = *(const short8*)(Qb + (size_t)srow * DHEAD + skoff);
    short8 qb = *(const short8*)(Qb + (size_t)(64 + srow) * DHEAD + skoff);
    *(short8*)((char*)Qt[0] + srow * 128 + ssw) = qa;
    *(short8*)((char*)Qt[0] + (64 + srow) * 128 + ssw) = qb;
    qa = *(const short8*)(Qb + (size_t)(128 + srow) * DHEAD + skoff);
    qb = *(const short8*)(Qb + (size_t)(192 + srow) * DHEAD + skoff);
    __syncthreads();

    for (int it = 0; it < 16; ++it) {
        const int q0 = it * 128;
        char* QtB = (char*)Qt[it & 1];
        char* QtN = (char*)Qt[(it & 1) ^ 1];

        if (it < 15) {
            *(short8*)(QtN + srow * 128 + ssw) = qa;
            *(short8*)(QtN + (64 + srow) * 128 + ssw) = qb;
            if (it < 14) {
                qa = *(const short8*)(Qb + (size_t)(q0 + 256 + srow) * DHEAD + skoff);
                qb = *(const short8*)(Qb + (size_t)(q0 + 320 + srow) * DHEAD + skoff);
            }
        }

        #pragma unroll
        for (int qi = 0; qi < 8; ++qi) {
            const int row = qi * 16 + l16;
            short8 a0 = *(const short8*)(QtB + row * 128 + ((q4 * 16) ^ rsw));
            short8 a1 = *(const short8*)(QtB + row * 128 + ((64 + q4 * 16) ^ rsw));
            __builtin_amdgcn_s_setprio(1);
            f32x4 s = MFMA16(a0, bk0, z);
            s = MFMA16(a1, bk1, s);
            __builtin_amdgcn_s_setprio(0);
            csum += ex2(s[0]) + ex2(s[1]) + ex2(s[2]) + ex2(s[3]);
        }
        __syncthreads();
    }
    csum += __shfl_xor(csum, 16, 64);
    csum += __shfl_xor(csum, 32, 64);
    if (q4 == 0) {
        const float c = 1.0f / csum;
        const int k = kcol0 + l16;
        colSrcp[(size_t)bh * NKEY + k] = c;
        // sigma-permuted bf16 write
        const int kloc = k & 31;
        const int nl = ((kloc & 15) >> 2) * 8 + ((kloc & 16) ? 4 : 0) + (kloc & 3);
        cbuf[(size_t)bh * NKEY + (k & ~31) + nl] = f2b(c);
    }
}

// ---------------------------------------------------------------------------
// Scale V rows by colSrcp in place: Vtb[bh][d][k] *= colSrcp[bh][k]  (bf16)
// ---------------------------------------------------------------------------
__launch_bounds__(256) __global__
void scale_v(unsigned short* __restrict__ Vtb, const float* __restrict__ colSrcp) {
    const size_t t8 = ((size_t)blockIdx.x * 256 + threadIdx.x) * 8;
    const int k = (int)(t8 & (NKEY - 1));
    const int bh = (int)(t8 >> 17);  // / (DHEAD * NKEY)
    const float* cs = colSrcp + ((size_t)bh << 11) + k;
    short8 v = *(const short8*)(Vtb + t8);
    float4 c0 = *(const float4*)cs;
    float4 c1 = *(const float4*)(cs + 4);
    short8 o;
    o[0] = (short)f2b(b2f((unsigned short)v[0]) * c0.x);
    o[1] = (short)f2b(b2f((unsigned short)v[1]) * c0.y);
    o[2] = (short)f2b(b2f((unsigned short)v[2]) * c0.z);
    o[3] = (short)f2b(b2f((unsigned short)v[3]) * c0.w);
    o[4] = (short)f2b(b2f((unsigned short)v[4]) * c1.x);
    o[5] = (short)f2b(b2f((unsigned short)v[5]) * c1.y);
    o[6] = (short)f2b(b2f((unsigned short)v[6]) * c1.z);
    o[7] = (short)f2b(b2f((unsigned short)v[7]) * c1.w);
    *(short8*)(Vtb + t8) = o;
}

// ---------------------------------------------------------------------------
// Pass 2: F = exp2(S'); O = F @ (cV); rq = F @ c; attnb = bf16(O/(1e-12+rq)).
// Zero-shuffle: swapped QK + sigma so a thread's QK outputs ARE its PV
// A-fragment (no E LDS round-trip). V is stored in LDS in SIGMA-PERMUTED
// k-order (within each 32-k/64B subgranule, group g = {4g..4g+3,16+4g..+3}
// contiguous 16B), so the PV B-fragment is ONE conflict-free ds_read_b128
// at the round-7-proven address pattern. Staging V = 4x ds_write_b64.
// K/V [128] dbuf; one barrier per 128 keys. LDS 64 KB.
// ---------------------------------------------------------------------------
__launch_bounds__(512) __global__
void attn_pass2(const unsigned short* __restrict__ Qh,
                const unsigned short* __restrict__ Kh,
                const unsigned short* __restrict__ Vt,   // pre-scaled by c
                const unsigned short* __restrict__ cb,   // bf16 c, sigma-permuted
                unsigned short* __restrict__ attnb) {
    __shared__ unsigned short Kt[2][128 * 64];     // 32 KB
    __shared__ unsigned short Vg[2][2][64 * 64];   // 32 KB (2 k-granules)
    const int tid = threadIdx.x;
    const int w = tid >> 6, lane = tid & 63;
    const int l16 = lane & 15, q4 = lane >> 4;
    const int bh = blockIdx.y;
    const int b = bh >> 3, h = bh & 7;
    const int q0w = blockIdx.x * 128 + w * 16;

    short8 aq0, aq1;
    {
        const unsigned short* Qrow = Qh + ((size_t)bh * NQ + q0w + l16) * DHEAD;
        aq0 = *(const short8*)(Qrow + q4 * 8);
        aq1 = *(const short8*)(Qrow + 32 + q4 * 8);
    }
    const unsigned short* Kb = Kh + (size_t)bh * NKEY * DHEAD;
    const unsigned short* Vb = Vt + (size_t)bh * DHEAD * NKEY;
    const unsigned short* cbb = cb + (size_t)bh * NKEY;

    const int srow = tid >> 3;            // 0..63
    const int skoff = (tid & 7) * 8;
    const int ssw = ((tid & 7) * 16) ^ ((srow & 7) << 4);
    const int rsw = (l16 & 7) << 4;
    // sigma-permuted V staging offsets (two b64 slots per short8)
    const int local32 = skoff & 31;                      // 0,8,16,24
    const int sub64v  = (skoff & 32) * 2;                // 0 or 64 bytes
    const int voff1 = sub64v + ((local32 >> 2) & 3) * 16 + ((local32 & 16) ? 8 : 0);
    const int rssw = (srow & 7) << 4;
    const int vsw1 = ((voff1 & 0x70) ^ rssw) | (voff1 & ~0x70);
    const int vsw2 = (((voff1 + 16) & 0x70) ^ rssw) | ((voff1 + 16) & ~0x70);

    f32x4 z = {0.f, 0.f, 0.f, 0.f};
    f32x4 o[4];
    #pragma unroll
    for (int t = 0; t < 4; ++t) o[t] = z;
    f32x4 o5 = z;  // rq accumulator

    // prologue: tile0 (k 0..127) -> buf0; tile1 into regs
    short8 kst[2], vst[2];
    kst[0] = *(const short8*)(Kb + (size_t)srow * DHEAD + skoff);
    kst[1] = *(const short8*)(Kb + (size_t)(64 + srow) * DHEAD + skoff);
    vst[0] = *(const short8*)(Vb + (size_t)srow * NKEY + skoff);
    vst[1] = *(const short8*)(Vb + (size_t)srow * NKEY + 64 + skoff);
    {
        char* K0 = (char*)&Kt[0][0];
        char* V0 = (char*)&Vg[0][0][0];
        *(short8*)(K0 + srow * 128 + ssw) = kst[0];
        *(short8*)(K0 + (64 + srow) * 128 + ssw) = kst[1];
        union { short8 s; uint4 u; } cv0, cv1;
        cv0.s = vst[0]; cv1.s = vst[1];
        *(uint2*)(V0 + srow * 128 + vsw1) = make_uint2(cv0.u.x, cv0.u.y);
        *(uint2*)(V0 + srow * 128 + vsw2) = make_uint2(cv0.u.z, cv0.u.w);
        *(uint2*)(V0 + 8192 + srow * 128 + vsw1) = make_uint2(cv1.u.x, cv1.u.y);
        *(uint2*)(V0 + 8192 + srow * 128 + vsw2) = make_uint2(cv1.u.z, cv1.u.w);
    }
    kst[0] = *(const short8*)(Kb + (size_t)(128 + srow) * DHEAD + skoff);
    kst[1] = *(const short8*)(Kb + (size_t)(192 + srow) * DHEAD + skoff);
    vst[0] = *(const short8*)(Vb + (size_t)srow * NKEY + 128 + skoff);
    vst[1] = *(const short8*)(Vb + (size_t)srow * NKEY + 192 + skoff);
    __syncthreads();

    for (int it = 0; it < 16; ++it) {
        const int kb = it * 128;
        char* KtB = (char*)&Kt[it & 1][0];
        char* VgB = (char*)&Vg[it & 1][0][0];

        if (it < 15) {  // stage tile it+1; prefetch tile it+2
            char* KtN = (char*)&Kt[(it & 1) ^ 1][0];
            char* VgN = (char*)&Vg[(it & 1) ^ 1][0][0];
            *(short8*)(KtN + srow * 128 + ssw) = kst[0];
            *(short8*)(KtN + (64 + srow) * 128 + ssw) = kst[1];
            union { short8 s; uint4 u; } cv0, cv1;
            cv0.s = vst[0]; cv1.s = vst[1];
            *(uint2*)(VgN + srow * 128 + vsw1) = make_uint2(cv0.u.x, cv0.u.y);
            *(uint2*)(VgN + srow * 128 + vsw2) = make_uint2(cv0.u.z, cv0.u.w);
            *(uint2*)(VgN + 8192 + srow * 128 + vsw1) = make_uint2(cv1.u.x, cv1.u.y);
            *(uint2*)(VgN + 8192 + srow * 128 + vsw2) = make_uint2(cv1.u.z, cv1.u.w);
            if (it < 14) {
                const int kn = kb + 256;
                kst[0] = *(const short8*)(Kb + (size_t)(kn + srow) * DHEAD + skoff);
                kst[1] = *(const short8*)(Kb + (size_t)(kn + 64 + srow) * DHEAD + skoff);
                vst[0] = *(const short8*)(Vb + (size_t)srow * NKEY + kn + skoff);
                vst[1] = *(const short8*)(Vb + (size_t)srow * NKEY + kn + 64 + skoff);
            }
        }

        #pragma unroll
        for (int sub = 0; sub < 4; ++sub) {
            // K fragments (A-operand rows = k)
            short8 bk[2][2];
            #pragma unroll
            for (int jt = 0; jt < 2; ++jt) {
                const int row = sub * 32 + jt * 16 + l16;
                bk[jt][0] = *(const short8*)(KtB + row * 128 + ((q4 * 16) ^ rsw));
                bk[jt][1] = *(const short8*)(KtB + row * 128 + ((64 + q4 * 16) ^ rsw));
            }
            // V fragments: sigma-permuted storage -> single b128, round-7 pattern
            short8 bv[4];
            #pragma unroll
            for (int t = 0; t < 4; ++t) {
                const char* vrow = VgB + (sub >> 1) * 8192 + (t * 16 + l16) * 128;
                bv[t] = *(const short8*)(vrow + (((sub & 1) * 64 + q4 * 16) ^ rsw));
            }
            // c fragment: sigma-permuted global -> single 16B load
            short8 c5 = *(const short8*)(cbb + kb + sub * 32 + q4 * 8);

            // Swapped QK: thread holds S'[q=l16][k = kb+sub*32+jt*16+q4*4+r]
            unsigned ew[4];
            #pragma unroll
            for (int jt = 0; jt < 2; ++jt) {
                __builtin_amdgcn_s_setprio(1);
                f32x4 st = MFMA16(bk[jt][0], aq0, z);
                st = MFMA16(bk[jt][1], aq1, st);
                __builtin_amdgcn_s_setprio(0);
                ew[jt * 2]     = pkbf(ex2(st[0]), ex2(st[1]));
                ew[jt * 2 + 1] = pkbf(ex2(st[2]), ex2(st[3]));
            }
            // ea slots {0..3} = jt0 (k = q4*4+0..3), {4..7} = jt1 (k = 16+q4*4+0..3)
            union { uint4 u; short8 s; } ea;
            ea.u = make_uint4(ew[0], ew[1], ew[2], ew[3]);

            __builtin_amdgcn_s_setprio(1);
            #pragma unroll
            for (int t = 0; t < 4; ++t)
                o[t] = MFMA16(ea.s, bv[t], o[t]);
            o5 = MFMA16(ea.s, c5, o5);
            __builtin_amdgcn_s_setprio(0);
        }
        __syncthreads();
    }

    float rr[4];
    #pragma unroll
    for (int r = 0; r < 4; ++r) rr[r] = 1.0f / (1e-12f + o5[r]);
    #pragma unroll
    for (int t = 0; t < 4; ++t)
        #pragma unroll
        for (int r = 0; r < 4; ++r) {
            const int q = q0w + q4 * 4 + r;
            attnb[((size_t)b * NQ + q) * DMODEL + h * DHEAD + t * 16 + l16] =
                f2b(o[t][r] * rr[r]);
        }
}

// ---------------------------------------------------------------------------
extern "C" void kernel_launch(void* const* d_in, const int* in_sizes, int n_in,
                              void* d_out, int out_size, void* d_ws, size_t ws_size,
                              hipStream_t stream) {
    const float* init_query = (const float*)d_in[0];
    const float* embedding  = (const float*)d_in[1];
    const float* Wq = (const float*)d_in[2];
    const float* Wk = (const float*)d_in[3];
    const float* Wv = (const float*)d_in[4];
    const float* W0 = (const float*)d_in[5];
    const float* b0 = (const float*)d_in[6];
    const float* W1 = (const float*)d_in[7];
    const float* b1 = (const float*)d_in[8];
    float* out = (float*)d_out;

    const size_t ACT = (size_t)BATCH * NQ * DMODEL;   // 4M elements
    const size_t WEL = (size_t)DMODEL * DMODEL;       // 256K elements

    unsigned short* Xq   = (unsigned short*)d_ws;          // bf16 init_query
    unsigned short* Xe   = Xq + ACT;                       // bf16 embedding
    unsigned short* Wt   = Xe + ACT;                       // 5 transposed weights
    unsigned short* Qh   = Wt + 5 * WEL;                   // [bh][q][d]
    unsigned short* Kh   = Qh + ACT;                       // [bh][k][d]
    unsigned short* Vtb  = Kh + ACT;                       // [bh][d][k]
    unsigned short* attnb= Vtb + ACT;                      // [8192][512]
    unsigned short* ybuf = attnb + ACT;                    // [8192][512]
    float* colSrcp = (float*)(ybuf + ACT);                 // [bh][k] f32

    // cbuf (bf16 c, sigma-permuted) aliases ybuf (dead until the W0-GEMM).
    unsigned short* cbuf = ybuf;

    unsigned short* W0t = Wt + 3 * WEL;
    unsigned short* W1t = Wt + 4 * WEL;

    const int M = BATCH * NQ;  // 8192
    dim3 blk(256);
    dim3 blk512(512);
    dim3 gGemm(M / 128, DMODEL / 64);  // 64 x 8

    cast_x<<<dim3(ACT / 1024, 2), blk, 0, stream>>>(init_query, embedding, Xq, Xe);
    trans_w<<<dim3(16, 16, 5), blk, 0, stream>>>(Wq, Wk, Wv, W0, W1, Wt);

    gemm_qkv<<<dim3(M / 128, DMODEL / 64, 3), blk, 0, stream>>>(Xq, Xe, Wt, Qh, Kh, Vtb);

    attn_pass1<<<dim3(NKEY / 128, BH), blk512, 0, stream>>>(Qh, Kh, colSrcp, cbuf);
    scale_v<<<dim3(ACT / 2048), blk, 0, stream>>>(Vtb, colSrcp);
    attn_pass2<<<dim3(NQ / 128, BH), blk512, 0, stream>>>(Qh, Kh, Vtb, cbuf, attnb);

    gemm_bf16<2><<<gGemm, blk, 0, stream>>>(attnb, W0t, ybuf, b0, init_query, M, DMODEL, DMODEL);
    gemm_bf16<3><<<gGemm, blk, 0, stream>>>(ybuf, W1t, out, b1, nullptr, M, DMODEL, DMODEL);
}